// Round 14
// baseline (568.257 us; speedup 1.0000x reference)
//
#include <hip/hip_runtime.h>
#include <math.h>

// ---- geometry constants (match reference) ----
#define NA   24
#define NU   128
#define NV   64
#define NW   128   // volume W (x)
#define NH   128   // volume H (y)
#define ND   64    // volume D (z)
#define NS   128   // samples per ray
#define F_STEP 1.5625f            // 2*HS/S = 200/128
#define F_DL  (200.0f / 127.0f)   // linspace(156,356,128) spacing
#define F_L0  156.0f
#define INV_DL (127.0f / 200.0f)

#define NRAYS (NA * NV * NU)      // 196608
#define VOX   (NW * NH * ND)      // 1048576
#define NSEG  4

// padded volume: planes {guard, padz(-1), z0..z63, padz(64), guard} x 130 x 130
#define PPX  130
#define PPY  130
#define PPZ  68
#define PPLANE (PPX * PPY)        // 16900
#define PVN  (PPZ * PPLANE)       // 1,149,200
#define CBASE (2 * PPLANE + PPX + 1)   // voxel(0,0,0) linear offset = 33931

typedef float v2f __attribute__((ext_vector_type(2)));

// cos/sin(k*15 deg)
__device__ __constant__ float CSA[NA] = {
    1.0f,  0.96592582628906829f,  0.86602540378443865f,  0.70710678118654752f,
    0.5f,  0.25881904510252076f,  0.0f,                 -0.25881904510252076f,
   -0.5f, -0.70710678118654752f, -0.86602540378443865f, -0.96592582628906829f,
   -1.0f, -0.96592582628906829f, -0.86602540378443865f, -0.70710678118654752f,
   -0.5f, -0.25881904510252076f,  0.0f,                  0.25881904510252076f,
    0.5f,  0.70710678118654752f,  0.86602540378443865f,  0.96592582628906829f
};
__device__ __constant__ float SNA[NA] = {
    0.0f,  0.25881904510252076f,  0.5f,                  0.70710678118654752f,
    0.86602540378443865f,  0.96592582628906829f,  1.0f,  0.96592582628906829f,
    0.86602540378443865f,  0.70710678118654752f,  0.5f,  0.25881904510252076f,
    0.0f, -0.25881904510252076f, -0.5f,                 -0.70710678118654752f,
   -0.86602540378443865f, -0.96592582628906829f, -1.0f, -0.96592582628906829f,
   -0.86602540378443865f, -0.70710678118654752f, -0.5f, -0.25881904510252076f
};

// ---------------- volume padding: zero borders, copy interior ----------------
__global__ __launch_bounds__(256) void pad_kernel(const float* __restrict__ vol,
                                                  float* __restrict__ padv) {
    int i = blockIdx.x * 256 + threadIdx.x;
    if (i >= PVN) return;
    int x = i % PPX;
    int t = i / PPX;
    int y = t % PPY;
    int z = t / PPY;
    float val = 0.0f;
    if (z >= 2 && z <= 65 && y >= 1 && y <= 128 && x >= 1 && x <= 128)
        val = vol[(((z - 2) << 7) + (y - 1) << 7) + (x - 1)];
    padv[i] = val;
}

// Per-ray geometry for FP.
__device__ __forceinline__ void ray_setup(int a, int v, int u,
                                          float& sx, float& sy,
                                          float& dx, float& dy, float& dz) {
    float ang = (float)((double)a * (15.0 * M_PI / 180.0));
    float c = cosf(ang), s = sinf(ang);
    float uu = (float)u - 63.5f;
    float vv = (float)v - 31.5f;
    float ux = 512.0f * c - uu * s;
    float uy = 512.0f * s + uu * c;
    float uz = vv;
    float invn = 1.0f / sqrtf(ux * ux + uy * uy + uz * uz);
    dx = ux * invn; dy = uy * invn; dz = uz * invn;
    sx = -256.0f * c; sy = -256.0f * s;
}

// ---------------- forward projection, 4 ell-segments, padded-volume gather ----------------
// All 8 loads unconditional (pads/guards absorb every out-of-range corner, incl.
// 1-ulp window slop); lerp-form trilinear; int32 addressing with imm offsets.
__global__ __launch_bounds__(256) void fp_seg_kernel(const float* __restrict__ padv,
                                                     float* __restrict__ part) {
    int r = blockIdx.x * blockDim.x + threadIdx.x;
    int seg = blockIdx.y;
    int u = r & (NU - 1);
    int v = (r >> 7) & (NV - 1);
    int a = r >> 13;

    float sx, sy, dx, dy, dz;
    ray_setup(a, v, u, sx, sy, dx, dy, dz);

    // exact-support window (voxel weights are zero outside +-64.5 / +-32.5)
    float rx = 1.0f / dx, ry = 1.0f / dy, rz = 1.0f / dz;
    float ex0 = (-64.51f - sx) * rx, ex1 = (64.51f - sx) * rx;
    float ey0 = (-64.51f - sy) * ry, ey1 = (64.51f - sy) * ry;
    float ez0 = (-32.51f) * rz,      ez1 = (32.51f) * rz;
    float llo = fmaxf(fmaxf(fminf(ex0, ex1), fminf(ey0, ey1)), fminf(ez0, ez1));
    float lhi = fminf(fminf(fmaxf(ex0, ex1), fmaxf(ey0, ey1)), fmaxf(ez0, ez1));
    int i_lo = max(seg * 32,      (int)ceilf((llo - F_L0) * INV_DL));
    int i_hi = min(seg * 32 + 31, (int)floorf((lhi - F_L0) * INV_DL));

    float acc = 0.0f;
    for (int i = i_lo; i <= i_hi; ++i) {
        float ell = fmaf((float)i, F_DL, F_L0);
        float cx = fmaf(ell, dx, sx) + 63.5f;   // voxel-index space
        float cy = fmaf(ell, dy, sy) + 63.5f;
        float cz = ell * dz + 31.5f;
        float fx = floorf(cx), fy = floorf(cy), fz = floorf(cz);
        int ix = (int)fx, iy = (int)fy, iz = (int)fz;
        float wx1 = cx - fx, wy1 = cy - fy, wz1 = cz - fz;
        int base = iz * PPLANE + iy * PPX + ix + CBASE;
        const float* q0 = padv + base;
        const float* q1 = q0 + PPLANE;
        float v000 = q0[0],   v001 = q0[1];
        float v010 = q0[PPX], v011 = q0[PPX + 1];
        float v100 = q1[0],   v101 = q1[1];
        float v110 = q1[PPX], v111 = q1[PPX + 1];
        float c00 = fmaf(wx1, v001 - v000, v000);
        float c01 = fmaf(wx1, v011 - v010, v010);
        float c10 = fmaf(wx1, v101 - v100, v100);
        float c11 = fmaf(wx1, v111 - v110, v110);
        float c0  = fmaf(wy1, c01 - c00, c00);
        float c1  = fmaf(wy1, c11 - c10, c10);
        acc += fmaf(wz1, c1 - c0, c0);
    }
    part[seg * NRAYS + r] = acc;
}

// ------- residual + cw + Ram-Lak; writes TRANSPOSED resT[a][u][v] -------
__global__ __launch_bounds__(NU) void ramp_kernel(const float* __restrict__ part,
                                                  const float* __restrict__ p,
                                                  float* __restrict__ resT) {
    __shared__ float row[NU];
    int rowid = blockIdx.x;          // a*NV + v
    int u = threadIdx.x;
    int e = rowid * NU + u;
    int a = rowid >> 6;
    int v = rowid & (NV - 1);
    float sino = (part[e] + part[NRAYS + e] + part[2 * NRAYS + e] + part[3 * NRAYS + e]) * F_STEP;
    double du = (double)u - 64.0;
    double dv = (double)v - 32.0;
    float cw = (float)(512.0 / sqrt(262144.0 + dv * dv + du * du));
    row[u] = (sino - p[e]) * cw;
    __syncthreads();
    float acc = 0.125f * row[u];
#pragma unroll
    for (int d = 1; d <= 63; d += 2) {
        float f = (float)(-0.5 / (M_PI * M_PI * (double)(d * d)));
        float lo = (u - d >= 0) ? row[u - d] : 0.0f;
        float hi = (u + d < NU) ? row[u + d] : 0.0f;
        acc += f * (lo + hi);
    }
    resT[(a << 13) + (u << 6) + v] = acc;   // [a][u][v]
}

// ---------------- back projection: adjacent-angle pair gather ----------------
// Wave = xy-column, lane = v. Angles (2j, 2j+1): 15deg apart -> near-identical
// u-windows -> shared u-grid (union, ~25% fewer wasted trips than opposite
// pairing) and shared arg/invn/nn (one rsq per pair). Two-ahead prefetch
// (load k+2) covers L2 latency; 3-bin register z-splat.

#define SETUP_ANGLE(S, AIDX)                                                     \
    const float c##S = CSA[AIDX], sn##S = SNA[AIDX];                             \
    const float ab##S = fabsf(c##S) + fabsf(sn##S);                              \
    const float c512##S = 512.0f * c##S;                                         \
    const float s512##S = 512.0f * sn##S;                                        \
    const float rho##S = fmaf(x0, c##S, fmaf(y0, sn##S, 256.0f));                \
    const float Vx##S = x0 + 256.0f * c##S;                                      \
    const float Vy##S = y0 + 256.0f * sn##S;                                     \
    const float tvlo##S = (rho##S - ab##S) * (1.0f / 512.0f);                    \
    const float yp##S = y0 * c##S - x0 * sn##S;                                  \
    const float rl##S = __builtin_amdgcn_rcpf(rho##S - ab##S);                   \
    const float rh##S = __builtin_amdgcn_rcpf(rho##S + ab##S);                   \
    const float A##S = yp##S - ab##S, B##S = yp##S + ab##S;                      \
    const float um##S = 512.0f * A##S * ((A##S >= 0.0f) ? rh##S : rl##S);        \
    const float uM##S = 512.0f * B##S * ((B##S >= 0.0f) ? rl##S : rh##S);        \
    const int u_lo##S = max(0,   (int)ceilf(um##S + 63.49f));                    \
    const int u_hi##S = min(127, (int)floorf(uM##S + 63.51f));                   \
    const float Zmin##S = fmaf(vvf, (vvf >= 0.0f) ? (tvlo##S - 1.0e-3f)          \
                                                  : (tvlo##S + 7.2e-3f), 31.5f); \
    const float izbf##S = floorf(Zmin##S);                                       \
    const int   izb##S  = (int)izbf##S;                                          \
    const v2f b0##S = {izbf##S, izbf##S};                                        \
    const float tDL##S = tvlo##S * INV_DL;                                       \
    const v2f mVx##S = {-Vx##S, -Vx##S}, mVy##S = {-Vy##S, -Vy##S};

#define BP_BODYS(S, RV, UU) do {                                                 \
    const float pu = fmaf(-(UU), sn##S, c512##S);                                \
    const float qu = fmaf((UU), c##S, s512##S);                                  \
    const float i0f  = ceilf(fmaf(tDL##S, nn, cK));                              \
    const float ell0 = fmaf(i0f, F_DL, F_L0);                                    \
    v2f tp; tp.x = ell0 * invn; tp.y = fmaf(F_DL, invn, tp.x);                   \
    const v2f pu2 = {pu, pu}, qu2 = {qu, qu};                                    \
    v2f wx = __builtin_elementwise_max(                                          \
        one2 - __builtin_elementwise_abs(__builtin_elementwise_fma(tp, pu2, mVx##S)), zero2); \
    v2f wy = __builtin_elementwise_max(                                          \
        one2 - __builtin_elementwise_abs(__builtin_elementwise_fma(tp, qu2, mVy##S)), zero2); \
    v2f val = wx * wy * (v2f){(RV), (RV)};                                       \
    const v2f fz2 = __builtin_elementwise_fma(tp, vv2, h31);                     \
    const v2f g = fz2 - b0##S;                                                   \
    AC0##S = __builtin_elementwise_fma(__builtin_elementwise_max(                \
             one2 - __builtin_elementwise_abs(g), zero2), val, AC0##S);          \
    AC1##S = __builtin_elementwise_fma(__builtin_elementwise_max(                \
             one2 - __builtin_elementwise_abs(g - one2), zero2), val, AC1##S);   \
    AC2##S = __builtin_elementwise_fma(__builtin_elementwise_max(                \
             one2 - __builtin_elementwise_abs(g - two2), zero2), val, AC2##S);   \
} while (0)

__global__ __launch_bounds__(256, 8) void bp_gather12(const float* __restrict__ resT,
                                                      float* __restrict__ out) {
    __shared__ float s_acc[4 * 64];       // per-wave z-accumulator columns

    const int tid  = threadIdx.x;
    const int lane = tid & 63;            // = v
    const int wv   = tid >> 6;            // wave 0..3
    const int y    = blockIdx.x & 127;    // y-major
    const int xq   = blockIdx.x >> 7;     // 0..31
    const int xi   = xq * 4 + wv;         // 4 consecutive x per block

    const float x0 = (float)xi - 63.5f;
    const float y0 = (float)y  - 63.5f;
    const float vvf = (float)lane - 31.5f;
    const float s2  = fmaf(vvf, vvf, 262144.0f);   // vv^2 + 512^2
    const v2f vv2   = {vvf, vvf};
    const v2f one2  = {1.0f, 1.0f}, zero2 = {0.0f, 0.0f};
    const v2f two2  = {2.0f, 2.0f};
    const v2f h31   = {31.5f, 31.5f};
    const float cK  = -(F_L0 * INV_DL) - 1.0e-3f;

    s_acc[tid] = 0.0f;

    for (int j = 0; j < NA / 2; ++j) {
        SETUP_ANGLE(0, 2 * j);            // adjacent pair: near-identical windows
        SETUP_ANGLE(1, 2 * j + 1);

        const int us = min(u_lo0, u_lo1);
        const int ue = max(u_hi0, u_hi1);
        const int trips = ue - us + 1;
        if (trips <= 0) continue;

        v2f AC00 = zero2, AC10 = zero2, AC20 = zero2;
        v2f AC01 = zero2, AC11 = zero2, AC21 = zero2;

        const float* ru0 = resT + ((2 * j) << 13)     + (us << 6) + lane;
        const float* ru1 = resT + ((2 * j + 1) << 13) + (us << 6) + lane;
        float uuf = (float)us - 63.5f;

        // two-ahead prefetch pipeline (over-reads stay inside ws)
        float Ar0 = ru0[0],  Ar1 = ru1[0];
        float Br0 = ru0[64], Br1 = ru1[64];
#pragma unroll 1
        for (int k = 0; k < trips; ++k) {
            const float Cr0 = ru0[128];
            const float Cr1 = ru1[128];
            // shared per-u geometry for the pair
            const float arg  = fmaf(uuf, uuf, s2);
            const float invn = __builtin_amdgcn_rsqf(arg);
            const float nn   = arg * invn;
            BP_BODYS(0, Ar0, uuf);
            BP_BODYS(1, Ar1, uuf);
            Ar0 = Br0; Ar1 = Br1; Br0 = Cr0; Br1 = Cr1;
            ru0 += 64; ru1 += 64;
            uuf += 1.0f;
        }

        float* accw = s_acc + (wv << 6);      // wave-private column
        atomicAdd(&accw[izb0],     AC00.x + AC00.y);
        atomicAdd(&accw[izb0 + 1], AC10.x + AC10.y);
        atomicAdd(&accw[izb0 + 2], AC20.x + AC20.y);
        atomicAdd(&accw[izb1],     AC01.x + AC01.y);
        atomicAdd(&accw[izb1 + 1], AC11.x + AC11.y);
        atomicAdd(&accw[izb1 + 2], AC21.x + AC21.y);
    }
    __syncthreads();

    // writeout: 4 consecutive x per 4 lanes -> 16B chunks
    const int z  = tid >> 2;
    const int w4 = tid & 3;
    out[(z << 14) + (y << 7) + xq * 4 + w4] = s_acc[(w4 << 6) + z] * F_STEP;
}

extern "C" void kernel_launch(void* const* d_in, const int* in_sizes, int n_in,
                              void* d_out, int out_size, void* d_ws, size_t ws_size,
                              hipStream_t stream) {
    const float* x = (const float*)d_in[0];   // [1,1,64,128,128]
    const float* p = (const float*)d_in[1];   // [1,1,24,64,128]
    float* out  = (float*)d_out;              // [1,1,64,128,128]
    float* resT = (float*)d_ws;               // transposed filtered residual, NRAYS floats
    float* part = resT + NRAYS;               // 4 FP segments, 4*NRAYS floats
    float* padv = part + NSEG * NRAYS;        // padded volume, PVN floats (~4.6 MB)

    pad_kernel<<<(PVN + 255) / 256, 256, 0, stream>>>(x, padv);
    dim3 fpg(NRAYS / 256, NSEG);
    fp_seg_kernel<<<fpg, 256, 0, stream>>>(padv, part);
    ramp_kernel<<<NA * NV, NU, 0, stream>>>(part, p, resT);
    bp_gather12<<<128 * 32, 256, 0, stream>>>(resT, out);
}

// Round 15
// 431.104 us; speedup vs baseline: 1.3181x; 1.3181x over previous
//
#include <hip/hip_runtime.h>
#include <math.h>

// ---- geometry constants (match reference) ----
#define NA   24
#define NU   128
#define NV   64
#define NW   128   // volume W (x)
#define NH   128   // volume H (y)
#define ND   64    // volume D (z)
#define NS   128   // samples per ray
#define F_STEP 1.5625f            // 2*HS/S = 200/128
#define F_DL  (200.0f / 127.0f)   // linspace(156,356,128) spacing
#define F_L0  156.0f
#define INV_DL (127.0f / 200.0f)

#define NRAYS (NA * NV * NU)      // 196608
#define VOX   (NW * NH * ND)      // 1048576
#define NSEG  4

// padded volume: planes {guard, padz(-1), z0..z63, padz(64), guard} x 130 x 130
#define PPX  130
#define PPY  130
#define PPZ  68
#define PPLANE (PPX * PPY)        // 16900
#define PVN  (PPZ * PPLANE)       // 1,149,200
#define CBASE (2 * PPLANE + PPX + 1)   // voxel(0,0,0) linear offset

typedef float v2f __attribute__((ext_vector_type(2)));

// cos/sin(k*15 deg)
__device__ __constant__ float CSA[NA] = {
    1.0f,  0.96592582628906829f,  0.86602540378443865f,  0.70710678118654752f,
    0.5f,  0.25881904510252076f,  0.0f,                 -0.25881904510252076f,
   -0.5f, -0.70710678118654752f, -0.86602540378443865f, -0.96592582628906829f,
   -1.0f, -0.96592582628906829f, -0.86602540378443865f, -0.70710678118654752f,
   -0.5f, -0.25881904510252076f,  0.0f,                  0.25881904510252076f,
    0.5f,  0.70710678118654752f,  0.86602540378443865f,  0.96592582628906829f
};
__device__ __constant__ float SNA[NA] = {
    0.0f,  0.25881904510252076f,  0.5f,                  0.70710678118654752f,
    0.86602540378443865f,  0.96592582628906829f,  1.0f,  0.96592582628906829f,
    0.86602540378443865f,  0.70710678118654752f,  0.5f,  0.25881904510252076f,
    0.0f, -0.25881904510252076f, -0.5f,                 -0.70710678118654752f,
   -0.86602540378443865f, -0.96592582628906829f, -1.0f, -0.96592582628906829f,
   -0.86602540378443865f, -0.70710678118654752f, -0.5f, -0.25881904510252076f
};

// ---------------- volume padding: zero borders, copy interior ----------------
__global__ __launch_bounds__(256) void pad_kernel(const float* __restrict__ vol,
                                                  float* __restrict__ padv) {
    int i = blockIdx.x * 256 + threadIdx.x;
    if (i >= PVN) return;
    int x = i % PPX;
    int t = i / PPX;
    int y = t % PPY;
    int z = t / PPY;
    float val = 0.0f;
    if (z >= 2 && z <= 65 && y >= 1 && y <= 128 && x >= 1 && x <= 128)
        val = vol[(((z - 2) << 7) + (y - 1) << 7) + (x - 1)];
    padv[i] = val;
}

// Per-ray geometry for FP.
__device__ __forceinline__ void ray_setup(int a, int v, int u,
                                          float& sx, float& sy,
                                          float& dx, float& dy, float& dz) {
    float ang = (float)((double)a * (15.0 * M_PI / 180.0));
    float c = cosf(ang), s = sinf(ang);
    float uu = (float)u - 63.5f;
    float vv = (float)v - 31.5f;
    float ux = 512.0f * c - uu * s;
    float uy = 512.0f * s + uu * c;
    float uz = vv;
    float invn = 1.0f / sqrtf(ux * ux + uy * uy + uz * uz);
    dx = ux * invn; dy = uy * invn; dz = uz * invn;
    sx = -256.0f * c; sy = -256.0f * s;
}

// ---------------- forward projection, 4 ell-segments, padded-volume gather ----------------
__global__ __launch_bounds__(256) void fp_seg_kernel(const float* __restrict__ padv,
                                                     float* __restrict__ part) {
    int r = blockIdx.x * blockDim.x + threadIdx.x;
    int seg = blockIdx.y;
    int u = r & (NU - 1);
    int v = (r >> 7) & (NV - 1);
    int a = r >> 13;

    float sx, sy, dx, dy, dz;
    ray_setup(a, v, u, sx, sy, dx, dy, dz);

    // exact-support window (voxel weights are zero outside +-64.5 / +-32.5)
    float rx = 1.0f / dx, ry = 1.0f / dy, rz = 1.0f / dz;
    float ex0 = (-64.51f - sx) * rx, ex1 = (64.51f - sx) * rx;
    float ey0 = (-64.51f - sy) * ry, ey1 = (64.51f - sy) * ry;
    float ez0 = (-32.51f) * rz,      ez1 = (32.51f) * rz;
    float llo = fmaxf(fmaxf(fminf(ex0, ex1), fminf(ey0, ey1)), fminf(ez0, ez1));
    float lhi = fminf(fminf(fmaxf(ex0, ex1), fmaxf(ey0, ey1)), fmaxf(ez0, ez1));
    int i_lo = max(seg * 32,      (int)ceilf((llo - F_L0) * INV_DL));
    int i_hi = min(seg * 32 + 31, (int)floorf((lhi - F_L0) * INV_DL));

    float acc = 0.0f;
    for (int i = i_lo; i <= i_hi; ++i) {
        float ell = fmaf((float)i, F_DL, F_L0);
        float cx = fmaf(ell, dx, sx) + 63.5f;   // voxel-index space
        float cy = fmaf(ell, dy, sy) + 63.5f;
        float cz = ell * dz + 31.5f;
        float fx = floorf(cx), fy = floorf(cy), fz = floorf(cz);
        int ix = (int)fx, iy = (int)fy, iz = (int)fz;
        float wx1 = cx - fx, wy1 = cy - fy, wz1 = cz - fz;
        int base = iz * PPLANE + iy * PPX + ix + CBASE;
        const float* q0 = padv + base;
        const float* q1 = q0 + PPLANE;
        float v000 = q0[0],   v001 = q0[1];
        float v010 = q0[PPX], v011 = q0[PPX + 1];
        float v100 = q1[0],   v101 = q1[1];
        float v110 = q1[PPX], v111 = q1[PPX + 1];
        float c00 = fmaf(wx1, v001 - v000, v000);
        float c01 = fmaf(wx1, v011 - v010, v010);
        float c10 = fmaf(wx1, v101 - v100, v100);
        float c11 = fmaf(wx1, v111 - v110, v110);
        float c0  = fmaf(wy1, c01 - c00, c00);
        float c1  = fmaf(wy1, c11 - c10, c10);
        acc += fmaf(wz1, c1 - c0, c0);
    }
    part[seg * NRAYS + r] = acc;
}

// ------- residual + cw + Ram-Lak; writes TRANSPOSED resT[a][u][v] -------
__global__ __launch_bounds__(NU) void ramp_kernel(const float* __restrict__ part,
                                                  const float* __restrict__ p,
                                                  float* __restrict__ resT) {
    __shared__ float row[NU];
    int rowid = blockIdx.x;          // a*NV + v
    int u = threadIdx.x;
    int e = rowid * NU + u;
    int a = rowid >> 6;
    int v = rowid & (NV - 1);
    float sino = (part[e] + part[NRAYS + e] + part[2 * NRAYS + e] + part[3 * NRAYS + e]) * F_STEP;
    double du = (double)u - 64.0;
    double dv = (double)v - 32.0;
    float cw = (float)(512.0 / sqrt(262144.0 + dv * dv + du * du));
    row[u] = (sino - p[e]) * cw;
    __syncthreads();
    float acc = 0.125f * row[u];
#pragma unroll
    for (int d = 1; d <= 63; d += 2) {
        float f = (float)(-0.5 / (M_PI * M_PI * (double)(d * d)));
        float lo = (u - d >= 0) ? row[u - d] : 0.0f;
        float hi = (u + d < NU) ? row[u + d] : 0.0f;
        acc += f * (lo + hi);
    }
    resT[(a << 13) + (u << 6) + v] = acc;   // [a][u][v]
}

// ---------------- back projection: adjacent-pair, separate u-grids ----------------
// R13 structure (each angle walks its OWN u-grid; trips = max of the two lengths)
// but pairing adjacent angles (2j, 2j+1) whose window LENGTHS nearly match
// (ab1 invariant under rotation, rho smooth) -> minimal max-trip waste, unlike
// opposite pairing (lengths anti-correlated) or R14's shared-grid union
// (centers ~50 u apart -> 3x VALU blowup). Two-ahead prefetch covers L2 latency.

#define SETUP_ANGLE(S, AIDX)                                                     \
    const float c##S = CSA[AIDX], sn##S = SNA[AIDX];                             \
    const float c512##S = 512.0f * c##S;                                         \
    const float s512##S = 512.0f * sn##S;                                        \
    const float rho##S = fmaf(x0, c##S, fmaf(y0, sn##S, 256.0f));                \
    const float Vx##S = x0 + 256.0f * c##S;                                      \
    const float Vy##S = y0 + 256.0f * sn##S;                                     \
    const float tvlo##S = (rho##S - ab1) * (1.0f / 512.0f);                      \
    const float yp##S = y0 * c##S - x0 * sn##S;                                  \
    const float rl##S = __builtin_amdgcn_rcpf(rho##S - ab1);                     \
    const float rh##S = __builtin_amdgcn_rcpf(rho##S + ab1);                     \
    const float A##S = yp##S - ab1, B##S = yp##S + ab1;                          \
    const float um##S = 512.0f * A##S * ((A##S >= 0.0f) ? rh##S : rl##S);        \
    const float uM##S = 512.0f * B##S * ((B##S >= 0.0f) ? rl##S : rh##S);        \
    const int u_lo##S = max(0,   (int)ceilf(um##S + 63.49f));                    \
    const int u_hi##S = min(127, (int)floorf(uM##S + 63.51f));                   \
    const int len##S = max(0, u_hi##S - u_lo##S + 1);                            \
    const float Zmin##S = fmaf(vvf, (vvf >= 0.0f) ? (tvlo##S - 1.0e-3f)          \
                                                  : (tvlo##S + 7.2e-3f), 31.5f); \
    const float izbf##S = floorf(Zmin##S);                                       \
    const int   izb##S  = (int)izbf##S;                                          \
    const v2f b0##S = {izbf##S, izbf##S};                                        \
    const float tDL##S = tvlo##S * INV_DL;                                       \
    const v2f mVx##S = {-Vx##S, -Vx##S}, mVy##S = {-Vy##S, -Vy##S};

#define BP_BODY2(S, RV, UU) do {                                                 \
    const float pu = fmaf(-(UU), sn##S, c512##S);                                \
    const float qu = fmaf((UU), c##S, s512##S);                                  \
    const float arg  = fmaf((UU), (UU), s2);                                     \
    const float invn = __builtin_amdgcn_rsqf(arg);                               \
    const float nn   = arg * invn;                                               \
    const float i0f  = ceilf(fmaf(tDL##S, nn, cK));                              \
    const float ell0 = fmaf(i0f, F_DL, F_L0);                                    \
    v2f tp; tp.x = ell0 * invn; tp.y = fmaf(F_DL, invn, tp.x);                   \
    const v2f pu2 = {pu, pu}, qu2 = {qu, qu};                                    \
    v2f wx = __builtin_elementwise_max(                                          \
        one2 - __builtin_elementwise_abs(__builtin_elementwise_fma(tp, pu2, mVx##S)), zero2); \
    v2f wy = __builtin_elementwise_max(                                          \
        one2 - __builtin_elementwise_abs(__builtin_elementwise_fma(tp, qu2, mVy##S)), zero2); \
    v2f val = wx * wy * (v2f){(RV), (RV)};                                       \
    const v2f fz2 = __builtin_elementwise_fma(tp, vv2, h31);                     \
    const v2f g = fz2 - b0##S;                                                   \
    AC0##S = __builtin_elementwise_fma(__builtin_elementwise_max(                \
             one2 - __builtin_elementwise_abs(g), zero2), val, AC0##S);          \
    AC1##S = __builtin_elementwise_fma(__builtin_elementwise_max(                \
             one2 - __builtin_elementwise_abs(g - one2), zero2), val, AC1##S);   \
    AC2##S = __builtin_elementwise_fma(__builtin_elementwise_max(                \
             one2 - __builtin_elementwise_abs(g - two2), zero2), val, AC2##S);   \
} while (0)

__global__ __launch_bounds__(256, 8) void bp_gather13(const float* __restrict__ resT,
                                                      float* __restrict__ out) {
    __shared__ float s_acc[4 * 64];       // per-wave z-accumulator columns

    const int tid  = threadIdx.x;
    const int lane = tid & 63;            // = v
    const int wv   = tid >> 6;            // wave 0..3
    const int y    = blockIdx.x & 127;    // y-major
    const int xq   = blockIdx.x >> 7;     // 0..31
    const int xi   = xq * 4 + wv;         // 4 consecutive x per block

    const float x0 = (float)xi - 63.5f;
    const float y0 = (float)y  - 63.5f;
    const float vvf = (float)lane - 31.5f;
    const float s2  = fmaf(vvf, vvf, 262144.0f);   // vv^2 + 512^2
    const v2f vv2   = {vvf, vvf};
    const v2f one2  = {1.0f, 1.0f}, zero2 = {0.0f, 0.0f};
    const v2f two2  = {2.0f, 2.0f};
    const v2f h31   = {31.5f, 31.5f};
    const float cK  = -(F_L0 * INV_DL) - 1.0e-3f;

    s_acc[tid] = 0.0f;

    for (int j = 0; j < NA / 2; ++j) {
        // ab1 = |c|+|s| is the same for both angles of an adjacent pair? Not
        // exactly, but both SETUPs need their own... use each angle's own:
        const float ab1a = fabsf(CSA[2 * j]) + fabsf(SNA[2 * j]);
        const float ab1b = fabsf(CSA[2 * j + 1]) + fabsf(SNA[2 * j + 1]);
        {
            const float ab1 = ab1a;
            SETUP_ANGLE(0, 2 * j);
            const float ab1_ = ab1b;
            #undef  AB_CUR
            #define AB_CUR ab1_
            // second setup with its own ab1 (shadow via block scope)
            const float c1 = CSA[2 * j + 1], sn1 = SNA[2 * j + 1];
            const float c5121 = 512.0f * c1;
            const float s5121 = 512.0f * sn1;
            const float rho1 = fmaf(x0, c1, fmaf(y0, sn1, 256.0f));
            const float Vx1 = x0 + 256.0f * c1;
            const float Vy1 = y0 + 256.0f * sn1;
            const float tvlo1 = (rho1 - ab1_) * (1.0f / 512.0f);
            const float yp1 = y0 * c1 - x0 * sn1;
            const float rl1 = __builtin_amdgcn_rcpf(rho1 - ab1_);
            const float rh1 = __builtin_amdgcn_rcpf(rho1 + ab1_);
            const float A1 = yp1 - ab1_, B1 = yp1 + ab1_;
            const float um1 = 512.0f * A1 * ((A1 >= 0.0f) ? rh1 : rl1);
            const float uM1 = 512.0f * B1 * ((B1 >= 0.0f) ? rl1 : rh1);
            const int u_lo1 = max(0,   (int)ceilf(um1 + 63.49f));
            const int u_hi1 = min(127, (int)floorf(uM1 + 63.51f));
            const int len1 = max(0, u_hi1 - u_lo1 + 1);
            const float Zmin1 = fmaf(vvf, (vvf >= 0.0f) ? (tvlo1 - 1.0e-3f)
                                                        : (tvlo1 + 7.2e-3f), 31.5f);
            const float izbf1 = floorf(Zmin1);
            const int   izb1  = (int)izbf1;
            const v2f b01 = {izbf1, izbf1};
            const float tDL1 = tvlo1 * INV_DL;
            const v2f mVx1 = {-Vx1, -Vx1}, mVy1 = {-Vy1, -Vy1};

            const int trips = max(len0, len1);
            if (trips == 0) continue;
            const int us0 = max(0, min(u_lo0, 128 - trips));
            const int us1 = max(0, min(u_lo1, 128 - trips));

            v2f AC00 = zero2, AC10 = zero2, AC20 = zero2;
            v2f AC01 = zero2, AC11 = zero2, AC21 = zero2;

            const float* ru0 = resT + ((2 * j) << 13)     + (us0 << 6) + lane;
            const float* ru1 = resT + ((2 * j + 1) << 13) + (us1 << 6) + lane;
            float uu0 = (float)us0 - 63.5f;
            float uu1 = (float)us1 - 63.5f;

            // two-ahead prefetch (over-reads stay inside ws: resT/part follow)
            float Ar0 = ru0[0],  Ar1 = ru1[0];
            float Br0 = ru0[64], Br1 = ru1[64];
#pragma unroll 1
            for (int k = 0; k < trips; ++k) {
                const float Cr0 = ru0[128];
                const float Cr1 = ru1[128];
                BP_BODY2(0, Ar0, uu0);
                BP_BODY2(1, Ar1, uu1);
                Ar0 = Br0; Ar1 = Br1; Br0 = Cr0; Br1 = Cr1;
                ru0 += 64; ru1 += 64;
                uu0 += 1.0f; uu1 += 1.0f;
            }

            float* accw = s_acc + (wv << 6);
            atomicAdd(&accw[izb0],     AC00.x + AC00.y);
            atomicAdd(&accw[izb0 + 1], AC10.x + AC10.y);
            atomicAdd(&accw[izb0 + 2], AC20.x + AC20.y);
            atomicAdd(&accw[izb1],     AC01.x + AC01.y);
            atomicAdd(&accw[izb1 + 1], AC11.x + AC11.y);
            atomicAdd(&accw[izb1 + 2], AC21.x + AC21.y);
        }
    }
    __syncthreads();

    // writeout: 4 consecutive x per 4 lanes -> 16B chunks
    const int z  = tid >> 2;
    const int w4 = tid & 3;
    out[(z << 14) + (y << 7) + xq * 4 + w4] = s_acc[(w4 << 6) + z] * F_STEP;
}

extern "C" void kernel_launch(void* const* d_in, const int* in_sizes, int n_in,
                              void* d_out, int out_size, void* d_ws, size_t ws_size,
                              hipStream_t stream) {
    const float* x = (const float*)d_in[0];   // [1,1,64,128,128]
    const float* p = (const float*)d_in[1];   // [1,1,24,64,128]
    float* out  = (float*)d_out;              // [1,1,64,128,128]
    float* resT = (float*)d_ws;               // transposed filtered residual, NRAYS floats
    float* part = resT + NRAYS;               // 4 FP segments, 4*NRAYS floats
    float* padv = part + NSEG * NRAYS;        // padded volume, PVN floats (~4.6 MB)

    pad_kernel<<<(PVN + 255) / 256, 256, 0, stream>>>(x, padv);
    dim3 fpg(NRAYS / 256, NSEG);
    fp_seg_kernel<<<fpg, 256, 0, stream>>>(padv, part);
    ramp_kernel<<<NA * NV, NU, 0, stream>>>(part, p, resT);
    bp_gather13<<<128 * 32, 256, 0, stream>>>(resT, out);
}

// Round 16
// 430.285 us; speedup vs baseline: 1.3207x; 1.0019x over previous
//
#include <hip/hip_runtime.h>
#include <math.h>

// ---- geometry constants (match reference) ----
#define NA   24
#define NU   128
#define NV   64
#define NW   128   // volume W (x)
#define NH   128   // volume H (y)
#define ND   64    // volume D (z)
#define NS   128   // samples per ray
#define F_STEP 1.5625f            // 2*HS/S = 200/128
#define F_DL  (200.0f / 127.0f)   // linspace(156,356,128) spacing
#define F_L0  156.0f
#define INV_DL (127.0f / 200.0f)

#define NRAYS (NA * NV * NU)      // 196608
#define VOX   (NW * NH * ND)      // 1048576
#define NSEG  4

// padded volume: planes {guard, padz(-1), z0..z63, padz(64), guard} x 130 x 130
#define PPX  130
#define PPY  130
#define PPZ  68
#define PPLANE (PPX * PPY)        // 16900
#define PVN  (PPZ * PPLANE)       // 1,149,200
#define CBASE (2 * PPLANE + PPX + 1)   // voxel(0,0,0) linear offset

typedef float v2f __attribute__((ext_vector_type(2)));

// cos/sin(k*15 deg)
__device__ __constant__ float CSA[NA] = {
    1.0f,  0.96592582628906829f,  0.86602540378443865f,  0.70710678118654752f,
    0.5f,  0.25881904510252076f,  0.0f,                 -0.25881904510252076f,
   -0.5f, -0.70710678118654752f, -0.86602540378443865f, -0.96592582628906829f,
   -1.0f, -0.96592582628906829f, -0.86602540378443865f, -0.70710678118654752f,
   -0.5f, -0.25881904510252076f,  0.0f,                  0.25881904510252076f,
    0.5f,  0.70710678118654752f,  0.86602540378443865f,  0.96592582628906829f
};
__device__ __constant__ float SNA[NA] = {
    0.0f,  0.25881904510252076f,  0.5f,                  0.70710678118654752f,
    0.86602540378443865f,  0.96592582628906829f,  1.0f,  0.96592582628906829f,
    0.86602540378443865f,  0.70710678118654752f,  0.5f,  0.25881904510252076f,
    0.0f, -0.25881904510252076f, -0.5f,                 -0.70710678118654752f,
   -0.86602540378443865f, -0.96592582628906829f, -1.0f, -0.96592582628906829f,
   -0.86602540378443865f, -0.70710678118654752f, -0.5f, -0.25881904510252076f
};

// ---------------- volume padding: zero borders, copy interior ----------------
__global__ __launch_bounds__(256) void pad_kernel(const float* __restrict__ vol,
                                                  float* __restrict__ padv) {
    int i = blockIdx.x * 256 + threadIdx.x;
    if (i >= PVN) return;
    int x = i % PPX;
    int t = i / PPX;
    int y = t % PPY;
    int z = t / PPY;
    float val = 0.0f;
    if (z >= 2 && z <= 65 && y >= 1 && y <= 128 && x >= 1 && x <= 128)
        val = vol[(((z - 2) << 7) + (y - 1) << 7) + (x - 1)];
    padv[i] = val;
}

// Per-ray geometry for FP.
__device__ __forceinline__ void ray_setup(int a, int v, int u,
                                          float& sx, float& sy,
                                          float& dx, float& dy, float& dz) {
    float ang = (float)((double)a * (15.0 * M_PI / 180.0));
    float c = cosf(ang), s = sinf(ang);
    float uu = (float)u - 63.5f;
    float vv = (float)v - 31.5f;
    float ux = 512.0f * c - uu * s;
    float uy = 512.0f * s + uu * c;
    float uz = vv;
    float invn = 1.0f / sqrtf(ux * ux + uy * uy + uz * uz);
    dx = ux * invn; dy = uy * invn; dz = uz * invn;
    sx = -256.0f * c; sy = -256.0f * s;
}

// ---------------- forward projection, 4 ell-segments, padded-volume gather ----------------
__global__ __launch_bounds__(256) void fp_seg_kernel(const float* __restrict__ padv,
                                                     float* __restrict__ part) {
    int r = blockIdx.x * blockDim.x + threadIdx.x;
    int seg = blockIdx.y;
    int u = r & (NU - 1);
    int v = (r >> 7) & (NV - 1);
    int a = r >> 13;

    float sx, sy, dx, dy, dz;
    ray_setup(a, v, u, sx, sy, dx, dy, dz);

    // exact-support window (voxel weights are zero outside +-64.5 / +-32.5)
    float rx = 1.0f / dx, ry = 1.0f / dy, rz = 1.0f / dz;
    float ex0 = (-64.51f - sx) * rx, ex1 = (64.51f - sx) * rx;
    float ey0 = (-64.51f - sy) * ry, ey1 = (64.51f - sy) * ry;
    float ez0 = (-32.51f) * rz,      ez1 = (32.51f) * rz;
    float llo = fmaxf(fmaxf(fminf(ex0, ex1), fminf(ey0, ey1)), fminf(ez0, ez1));
    float lhi = fminf(fminf(fmaxf(ex0, ex1), fmaxf(ey0, ey1)), fmaxf(ez0, ez1));
    int i_lo = max(seg * 32,      (int)ceilf((llo - F_L0) * INV_DL));
    int i_hi = min(seg * 32 + 31, (int)floorf((lhi - F_L0) * INV_DL));

    float acc = 0.0f;
    for (int i = i_lo; i <= i_hi; ++i) {
        float ell = fmaf((float)i, F_DL, F_L0);
        float cx = fmaf(ell, dx, sx) + 63.5f;   // voxel-index space
        float cy = fmaf(ell, dy, sy) + 63.5f;
        float cz = ell * dz + 31.5f;
        float fx = floorf(cx), fy = floorf(cy), fz = floorf(cz);
        int ix = (int)fx, iy = (int)fy, iz = (int)fz;
        float wx1 = cx - fx, wy1 = cy - fy, wz1 = cz - fz;
        int base = iz * PPLANE + iy * PPX + ix + CBASE;
        const float* q0 = padv + base;
        const float* q1 = q0 + PPLANE;
        float v000 = q0[0],   v001 = q0[1];
        float v010 = q0[PPX], v011 = q0[PPX + 1];
        float v100 = q1[0],   v101 = q1[1];
        float v110 = q1[PPX], v111 = q1[PPX + 1];
        float c00 = fmaf(wx1, v001 - v000, v000);
        float c01 = fmaf(wx1, v011 - v010, v010);
        float c10 = fmaf(wx1, v101 - v100, v100);
        float c11 = fmaf(wx1, v111 - v110, v110);
        float c0  = fmaf(wy1, c01 - c00, c00);
        float c1  = fmaf(wy1, c11 - c10, c10);
        acc += fmaf(wz1, c1 - c0, c0);
    }
    part[seg * NRAYS + r] = acc;
}

// ------- residual + cw + Ram-Lak; writes TRANSPOSED resT[a][u][v] -------
__global__ __launch_bounds__(NU) void ramp_kernel(const float* __restrict__ part,
                                                  const float* __restrict__ p,
                                                  float* __restrict__ resT) {
    __shared__ float row[NU];
    int rowid = blockIdx.x;          // a*NV + v
    int u = threadIdx.x;
    int e = rowid * NU + u;
    int a = rowid >> 6;
    int v = rowid & (NV - 1);
    float sino = (part[e] + part[NRAYS + e] + part[2 * NRAYS + e] + part[3 * NRAYS + e]) * F_STEP;
    double du = (double)u - 64.0;
    double dv = (double)v - 32.0;
    float cw = (float)(512.0 / sqrt(262144.0 + dv * dv + du * du));
    row[u] = (sino - p[e]) * cw;
    __syncthreads();
    float acc = 0.125f * row[u];
#pragma unroll
    for (int d = 1; d <= 63; d += 2) {
        float f = (float)(-0.5 / (M_PI * M_PI * (double)(d * d)));
        float lo = (u - d >= 0) ? row[u - d] : 0.0f;
        float hi = (u + d < NU) ? row[u + d] : 0.0f;
        acc += f * (lo + hi);
    }
    resT[(a << 13) + (u << 6) + v] = acc;   // [a][u][v]
}

// ---------------- back projection: adjacent-pair, 2x-unrolled, separate u-grids ----------------
// R15 structure (angles 2j, 2j+1 interleaved, own u-grids, trips = max length)
// unrolled by 2: 4 independent bodies/iter (u,u+1 per angle) -> 4 VALU chains
// per wave, halved loop/SALU overhead, load->use distance = 1 full iteration.
// Odd trips round up to even; extra column self-zeros; reads clamped <= 127+3
// over-read columns stay inside ws (part[] follows resT).

#define SETUP_ANGLE(S, AIDX, AB)                                                 \
    const float c##S = CSA[AIDX], sn##S = SNA[AIDX];                             \
    const float c512##S = 512.0f * c##S;                                         \
    const float s512##S = 512.0f * sn##S;                                        \
    const float rho##S = fmaf(x0, c##S, fmaf(y0, sn##S, 256.0f));                \
    const float Vx##S = x0 + 256.0f * c##S;                                      \
    const float Vy##S = y0 + 256.0f * sn##S;                                     \
    const float tvlo##S = (rho##S - (AB)) * (1.0f / 512.0f);                     \
    const float yp##S = y0 * c##S - x0 * sn##S;                                  \
    const float rl##S = __builtin_amdgcn_rcpf(rho##S - (AB));                    \
    const float rh##S = __builtin_amdgcn_rcpf(rho##S + (AB));                    \
    const float A##S = yp##S - (AB), B##S = yp##S + (AB);                        \
    const float um##S = 512.0f * A##S * ((A##S >= 0.0f) ? rh##S : rl##S);        \
    const float uM##S = 512.0f * B##S * ((B##S >= 0.0f) ? rl##S : rh##S);        \
    const int u_lo##S = max(0,   (int)ceilf(um##S + 63.49f));                    \
    const int u_hi##S = min(127, (int)floorf(uM##S + 63.51f));                   \
    const int len##S = max(0, u_hi##S - u_lo##S + 1);                            \
    const float Zmin##S = fmaf(vvf, (vvf >= 0.0f) ? (tvlo##S - 1.0e-3f)          \
                                                  : (tvlo##S + 7.2e-3f), 31.5f); \
    const float izbf##S = floorf(Zmin##S);                                       \
    const int   izb##S  = (int)izbf##S;                                          \
    const v2f b0##S = {izbf##S, izbf##S};                                        \
    const float tDL##S = tvlo##S * INV_DL;                                       \
    const v2f mVx##S = {-Vx##S, -Vx##S}, mVy##S = {-Vy##S, -Vy##S};

#define BP_BODY2(S, RV, UU) do {                                                 \
    const float pu = fmaf(-(UU), sn##S, c512##S);                                \
    const float qu = fmaf((UU), c##S, s512##S);                                  \
    const float arg  = fmaf((UU), (UU), s2);                                     \
    const float invn = __builtin_amdgcn_rsqf(arg);                               \
    const float nn   = arg * invn;                                               \
    const float i0f  = ceilf(fmaf(tDL##S, nn, cK));                              \
    const float ell0 = fmaf(i0f, F_DL, F_L0);                                    \
    v2f tp; tp.x = ell0 * invn; tp.y = fmaf(F_DL, invn, tp.x);                   \
    const v2f pu2 = {pu, pu}, qu2 = {qu, qu};                                    \
    v2f wx = __builtin_elementwise_max(                                          \
        one2 - __builtin_elementwise_abs(__builtin_elementwise_fma(tp, pu2, mVx##S)), zero2); \
    v2f wy = __builtin_elementwise_max(                                          \
        one2 - __builtin_elementwise_abs(__builtin_elementwise_fma(tp, qu2, mVy##S)), zero2); \
    v2f val = wx * wy * (v2f){(RV), (RV)};                                       \
    const v2f fz2 = __builtin_elementwise_fma(tp, vv2, h31);                     \
    const v2f g = fz2 - b0##S;                                                   \
    AC0##S = __builtin_elementwise_fma(__builtin_elementwise_max(                \
             one2 - __builtin_elementwise_abs(g), zero2), val, AC0##S);          \
    AC1##S = __builtin_elementwise_fma(__builtin_elementwise_max(                \
             one2 - __builtin_elementwise_abs(g - one2), zero2), val, AC1##S);   \
    AC2##S = __builtin_elementwise_fma(__builtin_elementwise_max(                \
             one2 - __builtin_elementwise_abs(g - two2), zero2), val, AC2##S);   \
} while (0)

__global__ __launch_bounds__(256, 8) void bp_gather14(const float* __restrict__ resT,
                                                      float* __restrict__ out) {
    __shared__ float s_acc[4 * 64];       // per-wave z-accumulator columns

    const int tid  = threadIdx.x;
    const int lane = tid & 63;            // = v
    const int wv   = tid >> 6;            // wave 0..3
    const int y    = blockIdx.x & 127;    // y-major
    const int xq   = blockIdx.x >> 7;     // 0..31
    const int xi   = xq * 4 + wv;         // 4 consecutive x per block

    const float x0 = (float)xi - 63.5f;
    const float y0 = (float)y  - 63.5f;
    const float vvf = (float)lane - 31.5f;
    const float s2  = fmaf(vvf, vvf, 262144.0f);   // vv^2 + 512^2
    const v2f vv2   = {vvf, vvf};
    const v2f one2  = {1.0f, 1.0f}, zero2 = {0.0f, 0.0f};
    const v2f two2  = {2.0f, 2.0f};
    const v2f h31   = {31.5f, 31.5f};
    const float cK  = -(F_L0 * INV_DL) - 1.0e-3f;

    s_acc[tid] = 0.0f;

    for (int j = 0; j < NA / 2; ++j) {
        const int a0 = 2 * j, a1 = 2 * j + 1;
        const float ab1a = fabsf(CSA[a0]) + fabsf(SNA[a0]);
        const float ab1b = fabsf(CSA[a1]) + fabsf(SNA[a1]);

        SETUP_ANGLE(0, a0, ab1a);         // adjacent pair: lengths nearly equal
        SETUP_ANGLE(1, a1, ab1b);

        const int trips = (max(len0, len1) + 1) & ~1;   // round up to even
        if (trips == 0) continue;
        const int us0 = max(0, min(u_lo0, 128 - trips));
        const int us1 = max(0, min(u_lo1, 128 - trips));

        v2f AC00 = zero2, AC10 = zero2, AC20 = zero2;
        v2f AC01 = zero2, AC11 = zero2, AC21 = zero2;

        const float* ru0 = resT + (a0 << 13) + (us0 << 6) + lane;
        const float* ru1 = resT + (a1 << 13) + (us1 << 6) + lane;
        float uu0 = (float)us0 - 63.5f;
        float uu1 = (float)us1 - 63.5f;

        // 2-column prefetch pipeline; over-reads (<=3 cols past) stay inside ws
        float Ar0 = ru0[0],  Ar1 = ru1[0];
        float Br0 = ru0[64], Br1 = ru1[64];
#pragma unroll 1
        for (int k = 0; k < trips; k += 2) {
            const float Cr0 = ru0[128];
            const float Cr1 = ru1[128];
            const float Dr0 = ru0[192];
            const float Dr1 = ru1[192];
            BP_BODY2(0, Ar0, uu0);
            BP_BODY2(1, Ar1, uu1);
            BP_BODY2(0, Br0, uu0 + 1.0f);
            BP_BODY2(1, Br1, uu1 + 1.0f);
            Ar0 = Cr0; Ar1 = Cr1; Br0 = Dr0; Br1 = Dr1;
            ru0 += 128; ru1 += 128;
            uu0 += 2.0f; uu1 += 2.0f;
        }

        float* accw = s_acc + (wv << 6);      // wave-private column
        atomicAdd(&accw[izb0],     AC00.x + AC00.y);
        atomicAdd(&accw[izb0 + 1], AC10.x + AC10.y);
        atomicAdd(&accw[izb0 + 2], AC20.x + AC20.y);
        atomicAdd(&accw[izb1],     AC01.x + AC01.y);
        atomicAdd(&accw[izb1 + 1], AC11.x + AC11.y);
        atomicAdd(&accw[izb1 + 2], AC21.x + AC21.y);
    }
    __syncthreads();

    // writeout: 4 consecutive x per 4 lanes -> 16B chunks
    const int z  = tid >> 2;
    const int w4 = tid & 3;
    out[(z << 14) + (y << 7) + xq * 4 + w4] = s_acc[(w4 << 6) + z] * F_STEP;
}

extern "C" void kernel_launch(void* const* d_in, const int* in_sizes, int n_in,
                              void* d_out, int out_size, void* d_ws, size_t ws_size,
                              hipStream_t stream) {
    const float* x = (const float*)d_in[0];   // [1,1,64,128,128]
    const float* p = (const float*)d_in[1];   // [1,1,24,64,128]
    float* out  = (float*)d_out;              // [1,1,64,128,128]
    float* resT = (float*)d_ws;               // transposed filtered residual, NRAYS floats
    float* part = resT + NRAYS;               // 4 FP segments, 4*NRAYS floats
    float* padv = part + NSEG * NRAYS;        // padded volume, PVN floats (~4.6 MB)

    pad_kernel<<<(PVN + 255) / 256, 256, 0, stream>>>(x, padv);
    dim3 fpg(NRAYS / 256, NSEG);
    fp_seg_kernel<<<fpg, 256, 0, stream>>>(padv, part);
    ramp_kernel<<<NA * NV, NU, 0, stream>>>(part, p, resT);
    bp_gather14<<<128 * 32, 256, 0, stream>>>(resT, out);
}